// Round 2
// baseline (2245.966 us; speedup 1.0000x reference)
//
#include <hip/hip_runtime.h>

typedef unsigned short ushort_t;

#define BN 4
#define SEQ 2048
#define DIM 1024
#define NH 16
#define HDIM 64
#define MROWS (BN*SEQ)   // 8192

__device__ __forceinline__ float bf2f(ushort_t s){ return __uint_as_float(((unsigned)s) << 16); }
__device__ __forceinline__ ushort_t f2bf(float f){
  unsigned u = __float_as_uint(f);
  u += 0x7fffu + ((u >> 16) & 1u);   // round-to-nearest-even
  return (ushort_t)(u >> 16);
}
__device__ __forceinline__ float bflo(unsigned u){ return __uint_as_float(u << 16); }
__device__ __forceinline__ float bfhi(unsigned u){ return __uint_as_float(u & 0xffff0000u); }
__device__ __forceinline__ void unpack16(uint4 a, uint4 b, float* f){
  f[0]=bflo(a.x); f[1]=bfhi(a.x); f[2]=bflo(a.y); f[3]=bfhi(a.y);
  f[4]=bflo(a.z); f[5]=bfhi(a.z); f[6]=bflo(a.w); f[7]=bfhi(a.w);
  f[8]=bflo(b.x); f[9]=bfhi(b.x); f[10]=bflo(b.y); f[11]=bfhi(b.y);
  f[12]=bflo(b.z); f[13]=bfhi(b.z); f[14]=bflo(b.w); f[15]=bfhi(b.w);
}

// ---------------- LayerNorm: one block per row (fp32 in -> bf16 out) --------
__global__ __launch_bounds__(256) void ln_kernel(const float* __restrict__ x,
    const float* __restrict__ gamma, const float* __restrict__ beta,
    ushort_t* __restrict__ xn)
{
  int row = blockIdx.x;
  int t = threadIdx.x;
  const float* xr = x + (size_t)row * DIM;
  float4 v = ((const float4*)xr)[t];
  float s = v.x+v.y+v.z+v.w;
  float ss = v.x*v.x+v.y*v.y+v.z*v.z+v.w*v.w;
  #pragma unroll
  for (int o = 32; o > 0; o >>= 1){ s += __shfl_down(s, o); ss += __shfl_down(ss, o); }
  __shared__ float red[8];
  __shared__ float stat[2];
  int wid = t >> 6;
  if ((t & 63) == 0){ red[wid] = s; red[4+wid] = ss; }
  __syncthreads();
  if (t == 0){
    float S0 = red[0]+red[1]+red[2]+red[3];
    float SS = red[4]+red[5]+red[6]+red[7];
    float mu = S0 * (1.f/DIM);
    float var = SS * (1.f/DIM) - mu*mu;
    stat[0] = mu; stat[1] = rsqrtf(var + 1e-5f);
  }
  __syncthreads();
  float mu = stat[0], rstd = stat[1];
  float4 g4 = ((const float4*)gamma)[t];
  float4 b4 = ((const float4*)beta)[t];
  ushort4 o;
  o.x = f2bf((v.x-mu)*rstd*g4.x + b4.x);
  o.y = f2bf((v.y-mu)*rstd*g4.y + b4.y);
  o.z = f2bf((v.z-mu)*rstd*g4.z + b4.z);
  o.w = f2bf((v.w-mu)*rstd*g4.w + b4.w);
  ((ushort4*)(xn + (size_t)row * DIM))[t] = o;
}

// ---------------- Tiled GEMM: C[M x N] = A_bf16[M x 1024] @ B_f32 + bias ----
// 64x64 block tile, 256 threads, 4x4 per thread.
// MODE 0: C fp32 row-major MxN.  MODE 1: C bf16 scatter to qkv (3,B,H,S,64).
template<int MODE, int NCOLS>
__global__ __launch_bounds__(256) void gemm_kernel(
    const ushort_t* __restrict__ A,
    const float* __restrict__ Bw,
    const float* __restrict__ bias,
    void* __restrict__ Cv)
{
  __shared__ float Ast[16][64];   // [k][m]
  __shared__ float Bs[16][64];    // [k][n]
  int t = threadIdx.x;
  int tx = t & 15, ty = t >> 4;
  int n0 = blockIdx.x * 64, m0 = blockIdx.y * 64;
  int ar = t >> 2, ak = (t & 3) * 4;
  int bk = t >> 4, bn = (t & 15) * 4;
  float acc[4][4] = {{0.f}};
  for (int k0 = 0; k0 < DIM; k0 += 16){
    ushort4 a4 = *(const ushort4*)(A + (size_t)(m0 + ar) * DIM + k0 + ak);
    float4 b4 = *(const float4*)(Bw + (size_t)(k0 + bk) * NCOLS + n0 + bn);
    Ast[ak+0][ar] = bf2f(a4.x);
    Ast[ak+1][ar] = bf2f(a4.y);
    Ast[ak+2][ar] = bf2f(a4.z);
    Ast[ak+3][ar] = bf2f(a4.w);
    *(float4*)&Bs[bk][bn] = b4;
    __syncthreads();
    #pragma unroll
    for (int kk = 0; kk < 16; kk++){
      float4 a = *(const float4*)&Ast[kk][ty*4];
      float4 b = *(const float4*)&Bs[kk][tx*4];
      acc[0][0] += a.x*b.x; acc[0][1] += a.x*b.y; acc[0][2] += a.x*b.z; acc[0][3] += a.x*b.w;
      acc[1][0] += a.y*b.x; acc[1][1] += a.y*b.y; acc[1][2] += a.y*b.z; acc[1][3] += a.y*b.w;
      acc[2][0] += a.z*b.x; acc[2][1] += a.z*b.y; acc[2][2] += a.z*b.z; acc[2][3] += a.z*b.w;
      acc[3][0] += a.w*b.x; acc[3][1] += a.w*b.y; acc[3][2] += a.w*b.z; acc[3][3] += a.w*b.w;
    }
    __syncthreads();
  }
  float bv[4];
  #pragma unroll
  for (int j = 0; j < 4; j++) bv[j] = bias[n0 + tx*4 + j];
  #pragma unroll
  for (int i = 0; i < 4; i++){
    int m = m0 + ty*4 + i;
    if (MODE == 0){
      float* C = (float*)Cv;
      float4 o = make_float4(acc[i][0]+bv[0], acc[i][1]+bv[1], acc[i][2]+bv[2], acc[i][3]+bv[3]);
      *(float4*)(C + (size_t)m * NCOLS + n0 + tx*4) = o;
    } else {
      ushort_t* C = (ushort_t*)Cv;
      ushort4 o;
      o.x = f2bf(acc[i][0] + bv[0]);
      o.y = f2bf(acc[i][1] + bv[1]);
      o.z = f2bf(acc[i][2] + bv[2]);
      o.w = f2bf(acc[i][3] + bv[3]);
      int which = n0 >> 10;           // 0..2 (tile never straddles: 64 | 1024)
      int h     = (n0 >> 6) & 15;
      int d     = tx * 4;
      int b_ = m >> 11, s_ = m & (SEQ-1);
      size_t idx = ((((size_t)which*BN + b_)*NH + h)*SEQ + s_)*HDIM + d;
      *(ushort4*)(C + idx) = o;
    }
  }
}

// ---------------- Flash attention: one block = (b,h) x 64 q-rows ------------
// 256 threads: thread = (q = t&63, g = t>>6); each owns O[q][16g..16g+15].
__global__ __launch_bounds__(256) void attn_kernel(const ushort_t* __restrict__ qkv,
                                                   ushort_t* __restrict__ ctx)
{
  __shared__ float   Qs[64][65];     // fp32, stride 65: scalar reads conflict-free
  __shared__ float   Kt[64][64];     // [d][k], float4 reads are wave-broadcast
  __shared__ float   Vs[64][64];     // [k][d], float4 reads are wave-broadcast
  __shared__ ushort_t Ps[64][68];    // bf16 P, stride 68: <=2-way (free)
  __shared__ float   redmax[4][64];
  __shared__ float   redsum[4][64];

  int t = threadIdx.x;
  int q = t & 63;
  int g = t >> 6;
  int qt = blockIdx.x & 31;          // 32 q-tiles
  int bh = blockIdx.x >> 5;          // b*NH + h

  const size_t PL = (size_t)BN * NH * SEQ * HDIM;   // 8388608
  const ushort_t* Qg = qkv + (size_t)bh * (SEQ * HDIM);
  const ushort_t* Kg = Qg + PL;
  const ushort_t* Vg = Qg + 2 * PL;

  {  // load Q tile (64x64)
    int r = t >> 2, d0 = (t & 3) * 16;
    const ushort_t* p = Qg + (size_t)(qt*64 + r) * HDIM + d0;
    uint4 u0 = *(const uint4*)p;
    uint4 u1 = *(const uint4*)(p + 8);
    float f[16]; unpack16(u0, u1, f);
    #pragma unroll
    for (int j = 0; j < 16; j++) Qs[r][d0 + j] = f[j];
  }

  float m = -1e30f, l = 0.f;
  float acc[16];
  #pragma unroll
  for (int j = 0; j < 16; j++) acc[j] = 0.f;

  for (int kt = 0; kt < 32; kt++){
    {  // load K,V tiles
      int r = t >> 2, d0 = (t & 3) * 16;
      const ushort_t* kp = Kg + (size_t)(kt*64 + r) * HDIM + d0;
      const ushort_t* vp = Vg + (size_t)(kt*64 + r) * HDIM + d0;
      uint4 ka = *(const uint4*)kp;  uint4 kb = *(const uint4*)(kp + 8);
      uint4 va = *(const uint4*)vp;  uint4 vb = *(const uint4*)(vp + 8);
      float kf[16]; unpack16(ka, kb, kf);
      #pragma unroll
      for (int j = 0; j < 16; j++) Kt[d0 + j][r] = kf[j];   // transpose K
      float vf[16]; unpack16(va, vb, vf);
      #pragma unroll
      for (int j4 = 0; j4 < 4; j4++)
        *(float4*)&Vs[r][d0 + 4*j4] = make_float4(vf[4*j4], vf[4*j4+1], vf[4*j4+2], vf[4*j4+3]);
    }
    __syncthreads();   // [A]

    float s[16];
    #pragma unroll
    for (int j = 0; j < 16; j++) s[j] = 0.f;
    for (int d = 0; d < 64; d++){
      float qd = Qs[q][d];
      const float* kp = &Kt[d][g*16];
      #pragma unroll
      for (int j4 = 0; j4 < 4; j4++){
        float4 kv = *(const float4*)(kp + 4*j4);
        s[4*j4+0] += qd*kv.x; s[4*j4+1] += qd*kv.y;
        s[4*j4+2] += qd*kv.z; s[4*j4+3] += qd*kv.w;
      }
    }
    float tmax = -1e30f;
    #pragma unroll
    for (int j = 0; j < 16; j++){ s[j] *= 0.125f; tmax = fmaxf(tmax, s[j]); }
    redmax[g][q] = tmax;
    __syncthreads();   // [B]
    float mt = fmaxf(fmaxf(redmax[0][q], redmax[1][q]), fmaxf(redmax[2][q], redmax[3][q]));
    float mnew = fmaxf(m, mt);
    float psum = 0.f;
    #pragma unroll
    for (int j = 0; j < 16; j++){
      float p = __expf(s[j] - mnew);
      Ps[q][g*16 + j] = f2bf(p);
      psum += p;
    }
    redsum[g][q] = psum;
    __syncthreads();   // [C]
    float rsum = redsum[0][q] + redsum[1][q] + redsum[2][q] + redsum[3][q];
    float alpha = __expf(m - mnew);
    l = l * alpha + rsum;
    m = mnew;
    #pragma unroll
    for (int j = 0; j < 16; j++) acc[j] *= alpha;
    for (int k = 0; k < 64; k++){
      float p = bf2f(Ps[q][k]);
      const float* vp = &Vs[k][g*16];
      #pragma unroll
      for (int j4 = 0; j4 < 4; j4++){
        float4 vv = *(const float4*)(vp + 4*j4);
        acc[4*j4+0] += p*vv.x; acc[4*j4+1] += p*vv.y;
        acc[4*j4+2] += p*vv.z; acc[4*j4+3] += p*vv.w;
      }
    }
    __syncthreads();   // [D]
  }

  float inv = 1.f / l;
  int b_ = bh >> 4, h_ = bh & 15;
  int srow = qt*64 + q;
  ushort_t* cp = ctx + ((size_t)(b_*SEQ + srow))*DIM + h_*HDIM + g*16;
  ushort4 o0, o1;
  o0.x = f2bf(acc[0]*inv);  o0.y = f2bf(acc[1]*inv);
  o0.z = f2bf(acc[2]*inv);  o0.w = f2bf(acc[3]*inv);
  o1.x = f2bf(acc[4]*inv);  o1.y = f2bf(acc[5]*inv);
  o1.z = f2bf(acc[6]*inv);  o1.w = f2bf(acc[7]*inv);
  *(ushort4*)cp = o0;
  *(ushort4*)(cp + 4) = o1;
  ushort4 o2, o3;
  o2.x = f2bf(acc[8]*inv);   o2.y = f2bf(acc[9]*inv);
  o2.z = f2bf(acc[10]*inv);  o2.w = f2bf(acc[11]*inv);
  o3.x = f2bf(acc[12]*inv);  o3.y = f2bf(acc[13]*inv);
  o3.z = f2bf(acc[14]*inv);  o3.w = f2bf(acc[15]*inv);
  *(ushort4*)(cp + 8)  = o2;
  *(ushort4*)(cp + 12) = o3;
}

extern "C" void kernel_launch(void* const* d_in, const int* in_sizes, int n_in,
                              void* d_out, int out_size, void* d_ws, size_t ws_size,
                              hipStream_t stream)
{
  const float* x      = (const float*)d_in[0];
  const float* gamma  = (const float*)d_in[1];
  const float* beta   = (const float*)d_in[2];
  const float* w_qkv  = (const float*)d_in[3];
  const float* b_qkv  = (const float*)d_in[4];
  const float* w_proj = (const float*)d_in[5];
  const float* b_proj = (const float*)d_in[6];

  ushort_t* xn  = (ushort_t*)d_ws;            // 8,388,608 bf16 (reused as ctx)
  ushort_t* qkv = xn + (size_t)MROWS * DIM;   // 25,165,824 bf16 (3,B,H,S,64)
  ushort_t* ctx = xn;                          // xn dead after QKV GEMM

  ln_kernel<<<MROWS, 256, 0, stream>>>(x, gamma, beta, xn);
  gemm_kernel<1, 3*DIM><<<dim3(3*DIM/64, MROWS/64), 256, 0, stream>>>(xn, w_qkv, b_qkv, qkv);
  attn_kernel<<<BN*NH*(SEQ/64), 256, 0, stream>>>(qkv, ctx);
  gemm_kernel<0, DIM><<<dim3(DIM/64, MROWS/64), 256, 0, stream>>>(ctx, w_proj, b_proj, d_out);
}

// Round 3
// 1206.537 us; speedup vs baseline: 1.8615x; 1.8615x over previous
//
#include <hip/hip_runtime.h>

typedef unsigned short ushort_t;
typedef __attribute__((ext_vector_type(8))) short bf16x8;
typedef __attribute__((ext_vector_type(4))) float f32x4;

#define BN 4
#define SEQ 2048
#define DIM 1024
#define NH 16
#define HDIM 64
#define MROWS (BN*SEQ)   // 8192

__device__ __forceinline__ float bf2f(ushort_t s){ return __uint_as_float(((unsigned)s) << 16); }
__device__ __forceinline__ ushort_t f2bf(float f){
  unsigned u = __float_as_uint(f);
  u += 0x7fffu + ((u >> 16) & 1u);   // round-to-nearest-even
  return (ushort_t)(u >> 16);
}

// ---------------- LayerNorm: one block per row (fp32 in -> bf16 out) --------
__global__ __launch_bounds__(256) void ln_kernel(const float* __restrict__ x,
    const float* __restrict__ gamma, const float* __restrict__ beta,
    ushort_t* __restrict__ xn)
{
  int row = blockIdx.x;
  int t = threadIdx.x;
  const float* xr = x + (size_t)row * DIM;
  float4 v = ((const float4*)xr)[t];
  float s = v.x+v.y+v.z+v.w;
  float ss = v.x*v.x+v.y*v.y+v.z*v.z+v.w*v.w;
  #pragma unroll
  for (int o = 32; o > 0; o >>= 1){ s += __shfl_down(s, o); ss += __shfl_down(ss, o); }
  __shared__ float red[8];
  __shared__ float stat[2];
  int wid = t >> 6;
  if ((t & 63) == 0){ red[wid] = s; red[4+wid] = ss; }
  __syncthreads();
  if (t == 0){
    float S0 = red[0]+red[1]+red[2]+red[3];
    float SS = red[4]+red[5]+red[6]+red[7];
    float mu = S0 * (1.f/DIM);
    float var = SS * (1.f/DIM) - mu*mu;
    stat[0] = mu; stat[1] = rsqrtf(var + 1e-5f);
  }
  __syncthreads();
  float mu = stat[0], rstd = stat[1];
  float4 g4 = ((const float4*)gamma)[t];
  float4 b4 = ((const float4*)beta)[t];
  ushort4 o;
  o.x = f2bf((v.x-mu)*rstd*g4.x + b4.x);
  o.y = f2bf((v.y-mu)*rstd*g4.y + b4.y);
  o.z = f2bf((v.z-mu)*rstd*g4.z + b4.z);
  o.w = f2bf((v.w-mu)*rstd*g4.w + b4.w);
  ((ushort4*)(xn + (size_t)row * DIM))[t] = o;
}

// ---------------- Tiled GEMM: C[M x N] = A_bf16[M x 1024] @ B_f32 + bias ----
// MODE 0: C fp32 row-major MxN.  MODE 1: C bf16 scatter to qkv (3,B,H,S,64).
template<int MODE, int NCOLS>
__global__ __launch_bounds__(256) void gemm_kernel(
    const ushort_t* __restrict__ A,
    const float* __restrict__ Bw,
    const float* __restrict__ bias,
    void* __restrict__ Cv)
{
  __shared__ float Ast[16][64];   // [k][m]
  __shared__ float Bs[16][64];    // [k][n]
  int t = threadIdx.x;
  int tx = t & 15, ty = t >> 4;
  int n0 = blockIdx.x * 64, m0 = blockIdx.y * 64;
  int ar = t >> 2, ak = (t & 3) * 4;
  int bk = t >> 4, bn = (t & 15) * 4;
  float acc[4][4] = {{0.f}};
  for (int k0 = 0; k0 < DIM; k0 += 16){
    ushort4 a4 = *(const ushort4*)(A + (size_t)(m0 + ar) * DIM + k0 + ak);
    float4 b4 = *(const float4*)(Bw + (size_t)(k0 + bk) * NCOLS + n0 + bn);
    Ast[ak+0][ar] = bf2f(a4.x);
    Ast[ak+1][ar] = bf2f(a4.y);
    Ast[ak+2][ar] = bf2f(a4.z);
    Ast[ak+3][ar] = bf2f(a4.w);
    *(float4*)&Bs[bk][bn] = b4;
    __syncthreads();
    #pragma unroll
    for (int kk = 0; kk < 16; kk++){
      float4 a = *(const float4*)&Ast[kk][ty*4];
      float4 b = *(const float4*)&Bs[kk][tx*4];
      acc[0][0] += a.x*b.x; acc[0][1] += a.x*b.y; acc[0][2] += a.x*b.z; acc[0][3] += a.x*b.w;
      acc[1][0] += a.y*b.x; acc[1][1] += a.y*b.y; acc[1][2] += a.y*b.z; acc[1][3] += a.y*b.w;
      acc[2][0] += a.z*b.x; acc[2][1] += a.z*b.y; acc[2][2] += a.z*b.z; acc[2][3] += a.z*b.w;
      acc[3][0] += a.w*b.x; acc[3][1] += a.w*b.y; acc[3][2] += a.w*b.z; acc[3][3] += a.w*b.w;
    }
    __syncthreads();
  }
  float bv[4];
  #pragma unroll
  for (int j = 0; j < 4; j++) bv[j] = bias[n0 + tx*4 + j];
  #pragma unroll
  for (int i = 0; i < 4; i++){
    int m = m0 + ty*4 + i;
    if (MODE == 0){
      float* C = (float*)Cv;
      float4 o = make_float4(acc[i][0]+bv[0], acc[i][1]+bv[1], acc[i][2]+bv[2], acc[i][3]+bv[3]);
      *(float4*)(C + (size_t)m * NCOLS + n0 + tx*4) = o;
    } else {
      ushort_t* C = (ushort_t*)Cv;
      ushort4 o;
      o.x = f2bf(acc[i][0] + bv[0]);
      o.y = f2bf(acc[i][1] + bv[1]);
      o.z = f2bf(acc[i][2] + bv[2]);
      o.w = f2bf(acc[i][3] + bv[3]);
      int which = n0 >> 10;
      int h     = (n0 >> 6) & 15;
      int d     = tx * 4;
      int b_ = m >> 11, s_ = m & (SEQ-1);
      size_t idx = ((((size_t)which*BN + b_)*NH + h)*SEQ + s_)*HDIM + d;
      *(ushort4*)(C + idx) = o;
    }
  }
}

// ---------------- MFMA flash attention -------------------------------------
// Block = one (b,h) x 64 q-rows; 4 waves x 16 q-rows.
// Per key-tile (64 keys): S = Q K^T (16x16x32 MFMA, A=Q preloaded, B from Ks),
// online softmax in S C-layout, P -> LDS (row-major), O^T += V^T P^T so both
// PV operands are contiguous b128 reads and alpha/l are scalar per lane.
__global__ __launch_bounds__(256) void attn_kernel(const ushort_t* __restrict__ qkv,
                                                   ushort_t* __restrict__ ctx)
{
  __shared__ ushort_t Ks[64][72];      // [key][dim], stride 72: 2-way only
  __shared__ ushort_t Vt[64][72];      // [dim][key]
  __shared__ ushort_t Ps[4][16][72];   // per-wave P (and epilogue O staging)

  int t = threadIdx.x;
  int lane = t & 63;
  int w = t >> 6;
  int col = lane & 15;
  int quad = lane >> 4;
  int qt = blockIdx.x & 31;
  int bh = blockIdx.x >> 5;

  const size_t PL = (size_t)BN * NH * SEQ * HDIM;
  const ushort_t* Qg = qkv + (size_t)bh * (SEQ * HDIM);
  const ushort_t* Kg = Qg + PL;
  const ushort_t* Vg = Qg + 2 * PL;

  // Q A-fragments (fixed for whole k-loop): rows = qt*64 + w*16 + col
  int qrow = qt*64 + w*16 + col;
  bf16x8 qfrag0 = *(const bf16x8*)(Qg + (size_t)qrow * HDIM + quad*8);
  bf16x8 qfrag1 = *(const bf16x8*)(Qg + (size_t)qrow * HDIM + 32 + quad*8);

  f32x4 acc_o[4];
  #pragma unroll
  for (int mt = 0; mt < 4; mt++) acc_o[mt] = (f32x4){0.f,0.f,0.f,0.f};
  float m_r[4], l_r[4];
  #pragma unroll
  for (int r = 0; r < 4; r++){ m_r[r] = -1e30f; l_r[r] = 0.f; }

  int src = (col >> 2) << 4;   // lane holding softmax state for row q=col
  int rr = col & 3;

  for (int kt = 0; kt < 32; kt++){
    { // ---- stage K (row-major) and V (transposed) ----
      int kr = t >> 2, kc = (t & 3) * 16;
      const ushort_t* kp = Kg + (size_t)(kt*64 + kr)*HDIM + kc;
      uint4 ka = *(const uint4*)kp;
      uint4 kb = *(const uint4*)(kp + 8);
      int vd = (t & 15) * 4, vr = (t >> 4) * 4;
      const ushort_t* vp = Vg + (size_t)(kt*64 + vr)*HDIM + vd;
      ushort4 v0 = *(const ushort4*)vp;
      ushort4 v1 = *(const ushort4*)(vp + HDIM);
      ushort4 v2 = *(const ushort4*)(vp + 2*HDIM);
      ushort4 v3 = *(const ushort4*)(vp + 3*HDIM);
      *(uint4*)&Ks[kr][kc]   = ka;
      *(uint4*)&Ks[kr][kc+8] = kb;
      *(ushort4*)&Vt[vd+0][vr] = make_ushort4(v0.x, v1.x, v2.x, v3.x);
      *(ushort4*)&Vt[vd+1][vr] = make_ushort4(v0.y, v1.y, v2.y, v3.y);
      *(ushort4*)&Vt[vd+2][vr] = make_ushort4(v0.z, v1.z, v2.z, v3.z);
      *(ushort4*)&Vt[vd+3][vr] = make_ushort4(v0.w, v1.w, v2.w, v3.w);
    }
    __syncthreads();

    // ---- S = Q K^T : 4 n-tiles of 16 keys, K=64 over 2 MFMAs ----
    f32x4 s[4];
    #pragma unroll
    for (int f = 0; f < 4; f++){
      bf16x8 k0 = *(const bf16x8*)&Ks[16*f + col][quad*8];
      bf16x8 k1 = *(const bf16x8*)&Ks[16*f + col][32 + quad*8];
      f32x4 a = (f32x4){0.f,0.f,0.f,0.f};
      a = __builtin_amdgcn_mfma_f32_16x16x32_bf16(qfrag0, k0, a, 0, 0, 0);
      a = __builtin_amdgcn_mfma_f32_16x16x32_bf16(qfrag1, k1, a, 0, 0, 0);
      s[f] = a;
    }

    // ---- online softmax (rows = quad*4+r, cols spread over 16 lanes x 4 f) ----
    float alpha_r[4];
    #pragma unroll
    for (int r = 0; r < 4; r++){
      float rmax = fmaxf(fmaxf(s[0][r], s[1][r]), fmaxf(s[2][r], s[3][r]));
      #pragma unroll
      for (int st = 1; st < 16; st <<= 1)
        rmax = fmaxf(rmax, __shfl_xor(rmax, st, 16));
      rmax *= 0.125f;
      float mnew = fmaxf(m_r[r], rmax);
      alpha_r[r] = __expf(m_r[r] - mnew);
      m_r[r] = mnew;
      float ps = 0.f;
      #pragma unroll
      for (int f = 0; f < 4; f++){
        float p = __expf(fmaf(s[f][r], 0.125f, -mnew));
        Ps[w][quad*4 + r][16*f + col] = f2bf(p);
        ps += p;
      }
      #pragma unroll
      for (int st = 1; st < 16; st <<= 1) ps += __shfl_xor(ps, st, 16);
      l_r[r] = l_r[r]*alpha_r[r] + ps;
    }

    // ---- rescale O^T by alpha for q=col (scalar per lane) ----
    float a0 = __shfl(alpha_r[0], src, 64);
    float a1 = __shfl(alpha_r[1], src, 64);
    float a2 = __shfl(alpha_r[2], src, 64);
    float a3 = __shfl(alpha_r[3], src, 64);
    float aq = rr == 0 ? a0 : (rr == 1 ? a1 : (rr == 2 ? a2 : a3));
    #pragma unroll
    for (int mt = 0; mt < 4; mt++)
      #pragma unroll
      for (int r = 0; r < 4; r++) acc_o[mt][r] *= aq;

    // ---- O^T += V^T P^T ----
    bf16x8 p0 = *(const bf16x8*)&Ps[w][col][quad*8];
    bf16x8 p1 = *(const bf16x8*)&Ps[w][col][32 + quad*8];
    #pragma unroll
    for (int mt = 0; mt < 4; mt++){
      bf16x8 va = *(const bf16x8*)&Vt[16*mt + col][quad*8];
      bf16x8 vb = *(const bf16x8*)&Vt[16*mt + col][32 + quad*8];
      acc_o[mt] = __builtin_amdgcn_mfma_f32_16x16x32_bf16(va, p0, acc_o[mt], 0, 0, 0);
      acc_o[mt] = __builtin_amdgcn_mfma_f32_16x16x32_bf16(vb, p1, acc_o[mt], 0, 0, 0);
    }
    __syncthreads();
  }

  // ---- epilogue: divide by l(q=col), stage O[q][dim] in LDS, coalesced store
  float l0 = __shfl(l_r[0], src, 64);
  float l1 = __shfl(l_r[1], src, 64);
  float l2 = __shfl(l_r[2], src, 64);
  float l3 = __shfl(l_r[3], src, 64);
  float lq = rr == 0 ? l0 : (rr == 1 ? l1 : (rr == 2 ? l2 : l3));
  float inv = 1.f / lq;
  #pragma unroll
  for (int mt = 0; mt < 4; mt++)
    #pragma unroll
    for (int r = 0; r < 4; r++)
      Ps[w][col][16*mt + quad*4 + r] = f2bf(acc_o[mt][r] * inv);

  int orow = lane >> 2, oc = (lane & 3) * 16;
  uint4 u0 = *(const uint4*)&Ps[w][orow][oc];
  uint4 u1 = *(const uint4*)&Ps[w][orow][oc + 8];
  int b_ = bh >> 4, h_ = bh & 15;
  int s_ = qt*64 + w*16 + orow;
  ushort_t* cp = ctx + ((size_t)(b_*SEQ + s_))*DIM + h_*HDIM + oc;
  *(uint4*)cp = u0;
  *(uint4*)(cp + 8) = u1;
}

extern "C" void kernel_launch(void* const* d_in, const int* in_sizes, int n_in,
                              void* d_out, int out_size, void* d_ws, size_t ws_size,
                              hipStream_t stream)
{
  const float* x      = (const float*)d_in[0];
  const float* gamma  = (const float*)d_in[1];
  const float* beta   = (const float*)d_in[2];
  const float* w_qkv  = (const float*)d_in[3];
  const float* b_qkv  = (const float*)d_in[4];
  const float* w_proj = (const float*)d_in[5];
  const float* b_proj = (const float*)d_in[6];

  ushort_t* xn  = (ushort_t*)d_ws;            // 8,388,608 bf16 (reused as ctx)
  ushort_t* qkv = xn + (size_t)MROWS * DIM;   // 25,165,824 bf16 (3,B,H,S,64)
  ushort_t* ctx = xn;                          // xn dead after QKV GEMM

  ln_kernel<<<MROWS, 256, 0, stream>>>(x, gamma, beta, xn);
  gemm_kernel<1, 3*DIM><<<dim3(3*DIM/64, MROWS/64), 256, 0, stream>>>(xn, w_qkv, b_qkv, qkv);
  attn_kernel<<<BN*NH*(SEQ/64), 256, 0, stream>>>(qkv, ctx);
  gemm_kernel<0, DIM><<<dim3(DIM/64, MROWS/64), 256, 0, stream>>>(ctx, w_proj, b_proj, d_out);
}

// Round 4
// 532.758 us; speedup vs baseline: 4.2157x; 2.2647x over previous
//
#include <hip/hip_runtime.h>

typedef unsigned short ushort_t;
typedef __attribute__((ext_vector_type(8))) short bf16x8;
typedef __attribute__((ext_vector_type(4))) float f32x4;

#define BN 4
#define SEQ 2048
#define DIM 1024
#define NH 16
#define HDIM 64
#define MROWS (BN*SEQ)   // 8192

__device__ __forceinline__ float bf2f(ushort_t s){ return __uint_as_float(((unsigned)s) << 16); }
__device__ __forceinline__ ushort_t f2bf(float f){
  unsigned u = __float_as_uint(f);
  u += 0x7fffu + ((u >> 16) & 1u);   // round-to-nearest-even
  return (ushort_t)(u >> 16);
}
__device__ __forceinline__ unsigned pack2(float a, float b){
  return (unsigned)f2bf(a) | ((unsigned)f2bf(b) << 16);
}

// ---------------- LN stats: one block per row -> (mu, rstd) -----------------
__global__ __launch_bounds__(256) void stats_kernel(const float* __restrict__ x,
                                                    float* __restrict__ stats)
{
  int row = blockIdx.x;
  int t = threadIdx.x;
  float4 v = ((const float4*)(x + (size_t)row * DIM))[t];
  float s = v.x+v.y+v.z+v.w;
  float ss = v.x*v.x+v.y*v.y+v.z*v.z+v.w*v.w;
  #pragma unroll
  for (int o = 32; o > 0; o >>= 1){ s += __shfl_down(s, o); ss += __shfl_down(ss, o); }
  __shared__ float red[8];
  int wid = t >> 6;
  if ((t & 63) == 0){ red[wid] = s; red[4+wid] = ss; }
  __syncthreads();
  if (t == 0){
    float S0 = red[0]+red[1]+red[2]+red[3];
    float SS = red[4]+red[5]+red[6]+red[7];
    float mu = S0 * (1.f/DIM);
    float var = SS * (1.f/DIM) - mu*mu;
    ((float2*)stats)[row] = make_float2(mu, rsqrtf(var + 1e-5f));
  }
}

// ---------------- transpose + fp32->bf16 convert: dst[n][k] = src[k][n] -----
__global__ __launch_bounds__(256) void cvt_t(const float* __restrict__ src,
                                             ushort_t* __restrict__ dst,
                                             int K, int N)
{
  __shared__ float tile[64][65];
  int k0 = blockIdx.y*64, n0 = blockIdx.x*64;
  int t = threadIdx.x;
  int c = (t & 15) * 4, r = t >> 4;   // 16 rows per pass
  #pragma unroll
  for (int p = 0; p < 4; p++){
    float4 v = *(const float4*)(src + (size_t)(k0 + r + p*16)*N + n0 + c);
    tile[r+p*16][c]   = v.x; tile[r+p*16][c+1] = v.y;
    tile[r+p*16][c+2] = v.z; tile[r+p*16][c+3] = v.w;
  }
  __syncthreads();
  #pragma unroll
  for (int p = 0; p < 4; p++){
    int nn = r + p*16;
    ushort4 o;
    o.x = f2bf(tile[c+0][nn]); o.y = f2bf(tile[c+1][nn]);
    o.z = f2bf(tile[c+2][nn]); o.w = f2bf(tile[c+3][nn]);
    *(ushort4*)(dst + (size_t)(n0+nn)*K + k0 + c) = o;
  }
}

// ---------------- MFMA GEMM: C[M x N] = A[M x 1024] @ BT^T + bias -----------
// 128x128 block tile, 256 thr = 4 waves, each wave 64x64 (4x4 of 16x16x32).
// BT is pre-transposed bf16 [N][1024].
// MODE 1: A = LayerNorm(x fp32) fused via stats/gamma/beta; C bf16 -> qkv scatter.
// MODE 0: A = bf16 row-major; C fp32 row-major + bias.
template<int MODE, int NCOLS>
__global__ __launch_bounds__(256) void mfma_gemm(
    const void* __restrict__ Av,
    const ushort_t* __restrict__ BT,
    const float* __restrict__ bias,
    const float* __restrict__ stats,
    const float* __restrict__ gamma,
    const float* __restrict__ beta,
    void* __restrict__ Cv)
{
  __shared__ __align__(16) unsigned char smem[MODE ? 24576 : 17408];
  ushort_t (*As)[128][8] = (ushort_t(*)[128][8])smem;            // 8 KB, kq-major
  ushort_t (*Bs)[128][8] = (ushort_t(*)[128][8])(smem + 8192);   // 8 KB
  float* gs  = (float*)(smem + 16384);                            // MODE1: 4 KB
  float* bs2 = gs + 1024;                                         // MODE1: 4 KB

  int t = threadIdx.x;
  int lane = t & 63, w = t >> 6;
  int col = lane & 15, quad = lane >> 4;
  int n0 = blockIdx.x * 128, m0 = blockIdx.y * 128;
  int sr = t >> 1, h = t & 1;          // staging: row (0..127), k-half (0..1)

  float mu = 0.f, rstd = 0.f;
  if (MODE == 1){
    *(float4*)&gs[t*4]  = ((const float4*)gamma)[t];
    *(float4*)&bs2[t*4] = ((const float4*)beta)[t];
    float2 st = ((const float2*)stats)[m0 + sr];
    mu = st.x; rstd = st.y;
  }

  f32x4 acc[4][4];
  #pragma unroll
  for (int i = 0; i < 4; i++)
    #pragma unroll
    for (int j = 0; j < 4; j++) acc[i][j] = (f32x4){0.f,0.f,0.f,0.f};

  int mbase = (w & 1)*64 + col;
  int nbase = (w >> 1)*64 + col;

  for (int k0 = 0; k0 < DIM; k0 += 32){
    // ---- global loads (coalesced: lane pairs cover one row's 32-k slice) ----
    uint4 aa0, aa1, bb0, bb1;
    float4 ax[4];
    if (MODE == 1){
      const float* xp = (const float*)Av + (size_t)(m0 + sr)*DIM + k0 + h*16;
      #pragma unroll
      for (int i = 0; i < 4; i++) ax[i] = *(const float4*)(xp + i*4);
    } else {
      const ushort_t* ap = (const ushort_t*)Av + (size_t)(m0 + sr)*DIM + k0 + h*16;
      aa0 = *(const uint4*)ap; aa1 = *(const uint4*)(ap + 8);
    }
    const ushort_t* bp = BT + (size_t)(n0 + sr)*DIM + k0 + h*16;
    bb0 = *(const uint4*)bp; bb1 = *(const uint4*)(bp + 8);

    __syncthreads();   // prev iter's frag reads done

    *(uint4*)&Bs[2*h  ][sr][0] = bb0;
    *(uint4*)&Bs[2*h+1][sr][0] = bb1;
    if (MODE == 1){
      float f[16];
      #pragma unroll
      for (int i = 0; i < 4; i++){
        float4 g = *(const float4*)&gs[k0 + h*16 + i*4];
        float4 b = *(const float4*)&bs2[k0 + h*16 + i*4];
        f[i*4+0] = (ax[i].x - mu)*rstd*g.x + b.x;
        f[i*4+1] = (ax[i].y - mu)*rstd*g.y + b.y;
        f[i*4+2] = (ax[i].z - mu)*rstd*g.z + b.z;
        f[i*4+3] = (ax[i].w - mu)*rstd*g.w + b.w;
      }
      uint4 p0, p1;
      p0.x = pack2(f[0],f[1]);  p0.y = pack2(f[2],f[3]);
      p0.z = pack2(f[4],f[5]);  p0.w = pack2(f[6],f[7]);
      p1.x = pack2(f[8],f[9]);  p1.y = pack2(f[10],f[11]);
      p1.z = pack2(f[12],f[13]); p1.w = pack2(f[14],f[15]);
      *(uint4*)&As[2*h  ][sr][0] = p0;
      *(uint4*)&As[2*h+1][sr][0] = p1;
    } else {
      *(uint4*)&As[2*h  ][sr][0] = aa0;
      *(uint4*)&As[2*h+1][sr][0] = aa1;
    }
    __syncthreads();

    // ---- fragments + MFMA ----
    bf16x8 af[4], bfr[4];
    #pragma unroll
    for (int i = 0; i < 4; i++){
      af[i]  = *(const bf16x8*)&As[quad][mbase + i*16][0];
      bfr[i] = *(const bf16x8*)&Bs[quad][nbase + i*16][0];
    }
    #pragma unroll
    for (int mt = 0; mt < 4; mt++)
      #pragma unroll
      for (int nt = 0; nt < 4; nt++)
        acc[mt][nt] = __builtin_amdgcn_mfma_f32_16x16x32_bf16(af[mt], bfr[nt], acc[mt][nt], 0, 0, 0);
  }

  // ---- epilogue ----
  float bv[4];
  #pragma unroll
  for (int nt = 0; nt < 4; nt++) bv[nt] = bias[n0 + (w>>1)*64 + nt*16 + col];

  if (MODE == 1){
    ushort_t (*Cs)[136] = (ushort_t(*)[136])smem;
    ushort_t* C = (ushort_t*)Cv;
    #pragma unroll
    for (int ph = 0; ph < 2; ph++){
      __syncthreads();
      if ((w & 1) == ph){
        #pragma unroll
        for (int mt = 0; mt < 4; mt++)
          #pragma unroll
          for (int nt = 0; nt < 4; nt++)
            #pragma unroll
            for (int r = 0; r < 4; r++)
              Cs[mt*16 + quad*4 + r][(w>>1)*64 + nt*16 + col] = f2bf(acc[mt][nt][r] + bv[nt]);
      }
      __syncthreads();
      #pragma unroll
      for (int p = 0; p < 4; p++){
        int id = p*256 + t;
        int row = id >> 4, cc = id & 15;
        uint4 u = *(const uint4*)&Cs[row][cc*8];
        int m = m0 + ph*64 + row;
        int n = n0 + cc*8;
        int which = n >> 10, hh = (n >> 6) & 15, d = n & 63;
        int b_ = m >> 11, s_ = m & (SEQ-1);
        *(uint4*)&C[((((size_t)which*BN + b_)*NH + hh)*SEQ + s_)*HDIM + d] = u;
      }
    }
  } else {
    float (*Cf)[132] = (float(*)[132])smem;
    float* C = (float*)Cv;
    #pragma unroll
    for (int ph = 0; ph < 4; ph++){
      __syncthreads();
      if ((w & 1) == (ph >> 1)){
        #pragma unroll
        for (int mi = 0; mi < 2; mi++){
          int mt = (ph & 1)*2 + mi;
          #pragma unroll
          for (int nt = 0; nt < 4; nt++)
            #pragma unroll
            for (int r = 0; r < 4; r++)
              Cf[mi*16 + quad*4 + r][(w>>1)*64 + nt*16 + col] = acc[mt][nt][r] + bv[nt];
        }
      }
      __syncthreads();
      #pragma unroll
      for (int p = 0; p < 4; p++){
        int id = p*256 + t;
        int row = id >> 5, cc = id & 31;
        float4 v = *(const float4*)&Cf[row][cc*4];
        int m = m0 + ph*32 + row;
        *(float4*)(C + (size_t)m*NCOLS + n0 + cc*4) = v;
      }
    }
  }
}

// ---------------- MFMA flash attention (verified round 3) -------------------
__global__ __launch_bounds__(256) void attn_kernel(const ushort_t* __restrict__ qkv,
                                                   ushort_t* __restrict__ ctx)
{
  __shared__ ushort_t Ks[64][72];
  __shared__ ushort_t Vt[64][72];
  __shared__ ushort_t Ps[4][16][72];

  int t = threadIdx.x;
  int lane = t & 63;
  int w = t >> 6;
  int col = lane & 15;
  int quad = lane >> 4;
  int qt = blockIdx.x & 31;
  int bh = blockIdx.x >> 5;

  const size_t PL = (size_t)BN * NH * SEQ * HDIM;
  const ushort_t* Qg = qkv + (size_t)bh * (SEQ * HDIM);
  const ushort_t* Kg = Qg + PL;
  const ushort_t* Vg = Qg + 2 * PL;

  int qrow = qt*64 + w*16 + col;
  bf16x8 qfrag0 = *(const bf16x8*)(Qg + (size_t)qrow * HDIM + quad*8);
  bf16x8 qfrag1 = *(const bf16x8*)(Qg + (size_t)qrow * HDIM + 32 + quad*8);

  f32x4 acc_o[4];
  #pragma unroll
  for (int mt = 0; mt < 4; mt++) acc_o[mt] = (f32x4){0.f,0.f,0.f,0.f};
  float m_r[4], l_r[4];
  #pragma unroll
  for (int r = 0; r < 4; r++){ m_r[r] = -1e30f; l_r[r] = 0.f; }

  int src = (col >> 2) << 4;
  int rr = col & 3;

  for (int kt = 0; kt < 32; kt++){
    {
      int kr = t >> 2, kc = (t & 3) * 16;
      const ushort_t* kp = Kg + (size_t)(kt*64 + kr)*HDIM + kc;
      uint4 ka = *(const uint4*)kp;
      uint4 kb = *(const uint4*)(kp + 8);
      int vd = (t & 15) * 4, vr = (t >> 4) * 4;
      const ushort_t* vp = Vg + (size_t)(kt*64 + vr)*HDIM + vd;
      ushort4 v0 = *(const ushort4*)vp;
      ushort4 v1 = *(const ushort4*)(vp + HDIM);
      ushort4 v2 = *(const ushort4*)(vp + 2*HDIM);
      ushort4 v3 = *(const ushort4*)(vp + 3*HDIM);
      *(uint4*)&Ks[kr][kc]   = ka;
      *(uint4*)&Ks[kr][kc+8] = kb;
      *(ushort4*)&Vt[vd+0][vr] = make_ushort4(v0.x, v1.x, v2.x, v3.x);
      *(ushort4*)&Vt[vd+1][vr] = make_ushort4(v0.y, v1.y, v2.y, v3.y);
      *(ushort4*)&Vt[vd+2][vr] = make_ushort4(v0.z, v1.z, v2.z, v3.z);
      *(ushort4*)&Vt[vd+3][vr] = make_ushort4(v0.w, v1.w, v2.w, v3.w);
    }
    __syncthreads();

    f32x4 s[4];
    #pragma unroll
    for (int f = 0; f < 4; f++){
      bf16x8 k0 = *(const bf16x8*)&Ks[16*f + col][quad*8];
      bf16x8 k1 = *(const bf16x8*)&Ks[16*f + col][32 + quad*8];
      f32x4 a = (f32x4){0.f,0.f,0.f,0.f};
      a = __builtin_amdgcn_mfma_f32_16x16x32_bf16(qfrag0, k0, a, 0, 0, 0);
      a = __builtin_amdgcn_mfma_f32_16x16x32_bf16(qfrag1, k1, a, 0, 0, 0);
      s[f] = a;
    }

    float alpha_r[4];
    #pragma unroll
    for (int r = 0; r < 4; r++){
      float rmax = fmaxf(fmaxf(s[0][r], s[1][r]), fmaxf(s[2][r], s[3][r]));
      #pragma unroll
      for (int st = 1; st < 16; st <<= 1)
        rmax = fmaxf(rmax, __shfl_xor(rmax, st, 16));
      rmax *= 0.125f;
      float mnew = fmaxf(m_r[r], rmax);
      alpha_r[r] = __expf(m_r[r] - mnew);
      m_r[r] = mnew;
      float ps = 0.f;
      #pragma unroll
      for (int f = 0; f < 4; f++){
        float p = __expf(fmaf(s[f][r], 0.125f, -mnew));
        Ps[w][quad*4 + r][16*f + col] = f2bf(p);
        ps += p;
      }
      #pragma unroll
      for (int st = 1; st < 16; st <<= 1) ps += __shfl_xor(ps, st, 16);
      l_r[r] = l_r[r]*alpha_r[r] + ps;
    }

    float a0 = __shfl(alpha_r[0], src, 64);
    float a1 = __shfl(alpha_r[1], src, 64);
    float a2 = __shfl(alpha_r[2], src, 64);
    float a3 = __shfl(alpha_r[3], src, 64);
    float aq = rr == 0 ? a0 : (rr == 1 ? a1 : (rr == 2 ? a2 : a3));
    #pragma unroll
    for (int mt = 0; mt < 4; mt++)
      #pragma unroll
      for (int r = 0; r < 4; r++) acc_o[mt][r] *= aq;

    bf16x8 p0 = *(const bf16x8*)&Ps[w][col][quad*8];
    bf16x8 p1 = *(const bf16x8*)&Ps[w][col][32 + quad*8];
    #pragma unroll
    for (int mt = 0; mt < 4; mt++){
      bf16x8 va = *(const bf16x8*)&Vt[16*mt + col][quad*8];
      bf16x8 vb = *(const bf16x8*)&Vt[16*mt + col][32 + quad*8];
      acc_o[mt] = __builtin_amdgcn_mfma_f32_16x16x32_bf16(va, p0, acc_o[mt], 0, 0, 0);
      acc_o[mt] = __builtin_amdgcn_mfma_f32_16x16x32_bf16(vb, p1, acc_o[mt], 0, 0, 0);
    }
    __syncthreads();
  }

  float l0 = __shfl(l_r[0], src, 64);
  float l1 = __shfl(l_r[1], src, 64);
  float l2 = __shfl(l_r[2], src, 64);
  float l3 = __shfl(l_r[3], src, 64);
  float lq = rr == 0 ? l0 : (rr == 1 ? l1 : (rr == 2 ? l2 : l3));
  float inv = 1.f / lq;
  #pragma unroll
  for (int mt = 0; mt < 4; mt++)
    #pragma unroll
    for (int r = 0; r < 4; r++)
      Ps[w][col][16*mt + quad*4 + r] = f2bf(acc_o[mt][r] * inv);

  int orow = lane >> 2, oc = (lane & 3) * 16;
  uint4 u0 = *(const uint4*)&Ps[w][orow][oc];
  uint4 u1 = *(const uint4*)&Ps[w][orow][oc + 8];
  int b_ = bh >> 4, h_ = bh & 15;
  int s_ = qt*64 + w*16 + orow;
  ushort_t* cp = ctx + ((size_t)(b_*SEQ + s_))*DIM + h_*HDIM + oc;
  *(uint4*)cp = u0;
  *(uint4*)(cp + 8) = u1;
}

extern "C" void kernel_launch(void* const* d_in, const int* in_sizes, int n_in,
                              void* d_out, int out_size, void* d_ws, size_t ws_size,
                              hipStream_t stream)
{
  const float* x      = (const float*)d_in[0];
  const float* gamma  = (const float*)d_in[1];
  const float* beta   = (const float*)d_in[2];
  const float* w_qkv  = (const float*)d_in[3];
  const float* b_qkv  = (const float*)d_in[4];
  const float* w_proj = (const float*)d_in[5];
  const float* b_proj = (const float*)d_in[6];

  // ws (64 MB), timeline-overlapped:
  //  [0,6M):   wqkvT   (live: QKV gemm)   -> overwritten by ctx
  //  [6M,+64K) stats   (live: QKV gemm)   -> overwritten by ctx
  //  [0,16M):  ctx     (written by attn)
  //  [16M,64M) qkv     (live: QKV gemm -> attn) -> head reused as wprojT
  char* ws = (char*)d_ws;
  ushort_t* wqkvT  = (ushort_t*)ws;
  float*    stats  = (float*)(ws + 6u*1024*1024);
  ushort_t* ctx    = (ushort_t*)ws;
  ushort_t* qkv    = (ushort_t*)(ws + 16u*1024*1024);
  ushort_t* wprojT = (ushort_t*)(ws + 16u*1024*1024);

  stats_kernel<<<MROWS, 256, 0, stream>>>(x, stats);
  cvt_t<<<dim3(3*DIM/64, DIM/64), 256, 0, stream>>>(w_qkv, wqkvT, DIM, 3*DIM);
  mfma_gemm<1, 3*DIM><<<dim3(3*DIM/128, MROWS/128), 256, 0, stream>>>(
      x, wqkvT, b_qkv, stats, gamma, beta, qkv);
  attn_kernel<<<BN*NH*(SEQ/64), 256, 0, stream>>>(qkv, ctx);
  cvt_t<<<dim3(DIM/64, DIM/64), 256, 0, stream>>>(w_proj, wprojT, DIM, DIM);
  mfma_gemm<0, DIM><<<dim3(DIM/128, MROWS/128), 256, 0, stream>>>(
      ctx, wprojT, b_proj, nullptr, nullptr, nullptr, d_out);
}